// Round 4
// baseline (588.865 us; speedup 1.0000x reference)
//
#include <hip/hip_runtime.h>
#include <cstdint>
#include <cstddef>

// Problem dims (fixed)
#define NN 131072      // nodes
#define EE 262144      // events
// msg GEMM: K = 448 = [mem_s 128 | mem_d 128 | raw 128 | tenc_s 32 | tenc_d 32], Nout = 256
// gru GEMM: K = 256 = [aggr 128 | memory 128], Nout = 512 = [r | z | i_n | h_n]

typedef __attribute__((ext_vector_type(8))) short bf16x8;
typedef __attribute__((ext_vector_type(4))) float f32x4;

__device__ __forceinline__ unsigned short f2bf(float f) {
    unsigned int u = __builtin_bit_cast(unsigned int, f);
    u += 0x7FFFu + ((u >> 16) & 1u);   // RNE
    return (unsigned short)(u >> 16);
}
__device__ __forceinline__ float bf2f(unsigned short s) {
    unsigned int u = ((unsigned int)s) << 16;
    return __builtin_bit_cast(float, u);
}
__device__ __forceinline__ float sigmoidf_(float x) { return 1.0f / (1.0f + __expf(-x)); }
__device__ __forceinline__ float tanhf_(float x) {
    float ax = fabsf(x);
    float e = __expf(-2.0f * ax);
    return copysignf((1.0f - e) / (1.0f + e), x);
}
__device__ __forceinline__ bf16x8 pack8(const float* f) {
    bf16x8 o;
#pragma unroll
    for (int i = 0; i < 8; ++i) o[i] = (short)f2bf(f[i]);
    return o;
}

// logical W' for the fused message GEMM (256 out x 448 in)
__device__ __forceinline__ float wmsg_val(int n, int k, const float* Ws, const float* Wd) {
    if (n < 128) {
        return (k < 416) ? Ws[n * 416 + k] : 0.0f;           // [mem_s, mem_d, raw, tenc_s]
    } else {
        int m = n - 128;
        if (k < 128)       return Wd[m * 416 + 128 + k];     // X' mem_s <- Wd block 1
        else if (k < 256)  return Wd[m * 416 + (k - 128)];   // X' mem_d <- Wd block 0
        else if (k < 384)  return Wd[m * 416 + k];           // raw
        else if (k < 416)  return 0.0f;                      // tenc_s unused by msg_d
        else               return Wd[m * 416 + 384 + (k - 416)]; // tenc_d
    }
}
// logical W for the GRU GEMM (512 out x 256 in)
__device__ __forceinline__ float wgru_val(int j, int k, const float* Wih, const float* Whh) {
    if (j < 256)      return (k < 128) ? Wih[j * 128 + k] : Whh[j * 128 + (k - 128)];
    else if (j < 384) return (k < 128) ? Wih[j * 128 + k] : 0.0f;
    else              return (k < 128) ? 0.0f : Whh[(j - 128) * 128 + (k - 128)];
}

// ---------------- prep: message weight in MFMA fragment order ----------------
__global__ void k_prep_msgfrag(const float* __restrict__ Ws, const float* __restrict__ Wd,
                               const float* __restrict__ bs, const float* __restrict__ bd,
                               unsigned short* __restrict__ Wmf, float* __restrict__ bm) {
    int b = blockIdx.x;              // c*16 + nt
    int c = b >> 4, nt = b & 15;
    int lane = threadIdx.x;
    int col0 = lane & 15, q = lane >> 4;
    int n = nt * 16 + col0;
    float f[8];
#pragma unroll
    for (int j = 0; j < 8; ++j) f[j] = wmsg_val(n, c * 32 + q * 8 + j, Ws, Wd);
    ((bf16x8*)Wmf)[(size_t)b * 64 + lane] = pack8(f);
    if (b == 0)
        for (int i = lane; i < 256; i += 64) bm[i] = (i < 128) ? bs[i] : bd[i - 128];
}

// ---------------- prep: GRU weight in MFMA fragment order ----------------
__global__ void k_prep_grufrag(const float* __restrict__ Wih, const float* __restrict__ Whh,
                               const float* __restrict__ bih, const float* __restrict__ bhh,
                               unsigned short* __restrict__ Wgf, float* __restrict__ bg) {
    int b = blockIdx.x;              // c*32 + nt
    int c = b >> 5, nt = b & 31;
    int lane = threadIdx.x;
    int col0 = lane & 15, q = lane >> 4;
    int j0 = nt * 16 + col0;
    float f[8];
#pragma unroll
    for (int j = 0; j < 8; ++j) f[j] = wgru_val(j0, c * 32 + q * 8 + j, Wih, Whh);
    ((bf16x8*)Wgf)[(size_t)b * 64 + lane] = pack8(f);
    if (b == 0)
        for (int i = lane; i < 512; i += 64)
            bg[i] = (i < 256) ? (bih[i] + bhh[i]) : ((i < 384) ? bih[i] : bhh[i - 128]);
}

// ---------------- memory fp32 -> bf16 table ----------------
__global__ void k_memconv(const float* __restrict__ in, unsigned short* __restrict__ outp) {
    int gid = blockIdx.x * 256 + threadIdx.x;
    const float4 v = ((const float4*)in)[gid];
    ushort4 o;
    o.x = f2bf(v.x); o.y = f2bf(v.y); o.z = f2bf(v.z); o.w = f2bf(v.w);
    *(ushort4*)(outp + (size_t)gid * 4) = o;
}

// ---------------- time encodings, bf16 [E,32] x2 ----------------
__global__ void k_tenc(const int* __restrict__ t, const int* __restrict__ src,
                       const int* __restrict__ dst, const int* __restrict__ lu,
                       const float* __restrict__ tw, const float* __restrict__ tb,
                       unsigned short* __restrict__ tenc_s, unsigned short* __restrict__ tenc_d) {
    int gid = blockIdx.x * 256 + threadIdx.x;   // E*64 threads
    int e = gid >> 6;
    int j = gid & 63;
    int jj = j & 31;
    int node = (j < 32) ? src[e] : dst[e];
    float tr = (float)(t[e] - lu[node]);
    unsigned short v = f2bf(__cosf(tr * tw[jj] + tb[jj]));
    if (j < 32) tenc_s[(size_t)e * 32 + jj] = v;
    else        tenc_d[(size_t)e * 32 + jj] = v;
}

// ---------------- counts + timestamp scatter-max ----------------
__global__ void k_pre(const int* __restrict__ src, const int* __restrict__ dst,
                      const int* __restrict__ t, int* cnt, int* lu_tmp) {
    int e = blockIdx.x * 256 + threadIdx.x;
    int s = src[e], d = dst[e], tv = t[e];
    atomicAdd(&cnt[s], 1);
    atomicAdd(&cnt[d], 1);
    atomicMax(&lu_tmp[s], tv);
    atomicMax(&lu_tmp[d], tv);
}

// ---------------- CSR scan: 3 stages ----------------
__global__ void k_scan1(const int* __restrict__ cnt, int* __restrict__ bsum) {
    __shared__ int red[256];
    int tid = threadIdx.x;
    red[tid] = cnt[blockIdx.x * 256 + tid];
    __syncthreads();
    for (int s = 128; s > 0; s >>= 1) {
        if (tid < s) red[tid] += red[tid + s];
        __syncthreads();
    }
    if (tid == 0) bsum[blockIdx.x] = red[0];
}
__global__ void k_scan2(const int* __restrict__ bsum, int* __restrict__ boff) {
    __shared__ int sb[512];
    int tid = threadIdx.x;
    int v = bsum[tid];
    sb[tid] = v;
    __syncthreads();
    for (int d = 1; d < 512; d <<= 1) {
        int u = (tid >= d) ? sb[tid - d] : 0;
        __syncthreads();
        sb[tid] += u;
        __syncthreads();
    }
    boff[tid] = sb[tid] - v;   // exclusive
}
__global__ void k_scan3(const int* __restrict__ cnt, const int* __restrict__ boff,
                        int* __restrict__ off, int* __restrict__ cursor) {
    __shared__ int sb[256];
    int tid = threadIdx.x;
    int i = blockIdx.x * 256 + tid;
    int v = cnt[i];
    sb[tid] = v;
    __syncthreads();
    for (int d = 1; d < 256; d <<= 1) {
        int u = (tid >= d) ? sb[tid - d] : 0;
        __syncthreads();
        sb[tid] += u;
        __syncthreads();
    }
    int o = boff[blockIdx.x] + sb[tid] - v;
    off[i] = o;
    cursor[i] = o;
}
// inverse permutation: event-side -> sorted position
__global__ void k_fill(const int* __restrict__ src, const int* __restrict__ dst,
                       int* cursor, int* __restrict__ pos2) {
    int e2 = blockIdx.x * 256 + threadIdx.x;   // [0,2E): <E = s-side, >=E = d-side
    int node = (e2 < EE) ? src[e2] : dst[e2 - EE];
    pos2[e2] = atomicAdd(&cursor[node], 1);
}

// ---------------- message GEMM -> msg_sorted[2E][128] bf16 ----------------
// 128 events x 256 outputs, K=448 in 14 chunks. Pipelined: issue(c+1) globals,
// run MFMA(c), then commit(c+1) to LDS. B frags prefetched one chunk ahead.
__launch_bounds__(256, 2)
__global__ void k_msg(const unsigned short* __restrict__ memb,
                      const float* __restrict__ raw,
                      const unsigned short* __restrict__ tenc_s,
                      const unsigned short* __restrict__ tenc_d,
                      const unsigned short* __restrict__ Wmf,
                      const float* __restrict__ bm,
                      const int* __restrict__ src, const int* __restrict__ dst,
                      const int* __restrict__ pos2,
                      unsigned short* __restrict__ msg) {
    __shared__ int s_idx[128], d_idx[128], s_pos[128], d_pos[128];
    __shared__ __align__(16) unsigned short As[2][5120];  // 128 x 32 tile, stride 40

    const int tid = threadIdx.x;
    const int e0 = blockIdx.x * 128;
    if (tid < 128) { s_idx[tid] = src[e0 + tid]; s_pos[tid] = pos2[e0 + tid]; }
    else { d_idx[tid - 128] = dst[e0 + tid - 128]; d_pos[tid - 128] = pos2[EE + e0 + tid - 128]; }
    __syncthreads();

    const int lane = tid & 63, w = tid >> 6;
    const int col0 = lane & 15, q = lane >> 4;

    bf16x8 sreg[2];
    float4 rreg[4];

    auto issue = [&](int cc) {
        if (cc < 8) {
#pragma unroll
            for (int i = 0; i < 2; ++i) {
                int lin = tid + 256 * i, row = lin >> 2, seg = lin & 3;
                int node = (cc < 4) ? s_idx[row] : d_idx[row];
                sreg[i] = *(const bf16x8*)(memb + (size_t)node * 128 + (cc & 3) * 32 + seg * 8);
            }
        } else if (cc < 12) {
#pragma unroll
            for (int i = 0; i < 4; ++i) {
                int lin = tid + 256 * i, row = lin >> 3, seg = lin & 7;
                rreg[i] = *(const float4*)(raw + (size_t)(e0 + row) * 128 + (cc - 8) * 32 + seg * 4);
            }
        } else {
            const unsigned short* tp = (cc == 12) ? tenc_s : tenc_d;
#pragma unroll
            for (int i = 0; i < 2; ++i) {
                int lin = tid + 256 * i, row = lin >> 2, seg = lin & 3;
                sreg[i] = *(const bf16x8*)(tp + (size_t)(e0 + row) * 32 + seg * 8);
            }
        }
    };
    auto commit = [&](int cc) {
        unsigned short* A = As[cc & 1];
        if (cc < 8 || cc >= 12) {
#pragma unroll
            for (int i = 0; i < 2; ++i) {
                int lin = tid + 256 * i, row = lin >> 2, seg = lin & 3;
                *(bf16x8*)&A[row * 40 + seg * 8] = sreg[i];
            }
        } else {
#pragma unroll
            for (int i = 0; i < 4; ++i) {
                int lin = tid + 256 * i, row = lin >> 3, seg = lin & 7;
                ushort4 o;
                o.x = f2bf(rreg[i].x); o.y = f2bf(rreg[i].y);
                o.z = f2bf(rreg[i].z); o.w = f2bf(rreg[i].w);
                *(ushort4*)&A[row * 40 + seg * 4] = o;
            }
        }
    };

    f32x4 acc[8][4];
#pragma unroll
    for (int a = 0; a < 8; ++a)
#pragma unroll
        for (int b = 0; b < 4; ++b)
#pragma unroll
            for (int i = 0; i < 4; ++i) acc[a][b][i] = 0.0f;

    const bf16x8* WmfV = (const bf16x8*)Wmf;
    bf16x8 bcur[4], bnxt[4];
#pragma unroll
    for (int nl = 0; nl < 4; ++nl)
        bcur[nl] = WmfV[(size_t)(0 * 16 + w * 4 + nl) * 64 + lane];
    issue(0);
    commit(0);
    __syncthreads();

    for (int c = 0; c < 14; ++c) {
        if (c < 13) {
#pragma unroll
            for (int nl = 0; nl < 4; ++nl)
                bnxt[nl] = WmfV[(size_t)((c + 1) * 16 + w * 4 + nl) * 64 + lane];
            issue(c + 1);
        }
        const unsigned short* A = As[c & 1];
        bf16x8 afr[8];
#pragma unroll
        for (int mt = 0; mt < 8; ++mt)
            afr[mt] = *(const bf16x8*)&A[(mt * 16 + col0) * 40 + q * 8];
#pragma unroll
        for (int mt = 0; mt < 8; ++mt)
#pragma unroll
            for (int nl = 0; nl < 4; ++nl)
                acc[mt][nl] = __builtin_amdgcn_mfma_f32_16x16x32_bf16(afr[mt], bcur[nl], acc[mt][nl], 0, 0, 0);
        if (c < 13) commit(c + 1);
        __syncthreads();
#pragma unroll
        for (int nl = 0; nl < 4; ++nl) bcur[nl] = bnxt[nl];
    }

    // epilogue: bias+relu, LDS transpose (stride 136), coalesced 64 B stores.
    float bv[4];
#pragma unroll
    for (int nl = 0; nl < 4; ++nl) bv[nl] = bm[(w * 4 + nl) * 16 + col0];
    unsigned short* C = &As[0][0];   // 64 rows x 136 ush = 17408 B <= 20480
#pragma unroll
    for (int p = 0; p < 4; ++p) {
        __syncthreads();
        const bool s_side = (p < 2);
        const int evb = (p & 1) * 64;
        if ((w < 2) == s_side) {
#pragma unroll
            for (int nl = 0; nl < 4; ++nl) {
                int jj = ((w & 1) * 4 + nl) * 16 + col0;
#pragma unroll
                for (int mt2 = 0; mt2 < 4; ++mt2) {
                    int mt = (p & 1) * 4 + mt2;
#pragma unroll
                    for (int r = 0; r < 4; ++r) {
                        int lr = mt2 * 16 + q * 4 + r;
                        float v = fmaxf(acc[mt][nl][r] + bv[nl], 0.0f);
                        C[lr * 136 + jj] = f2bf(v);
                    }
                }
            }
        }
        __syncthreads();
        int lr = tid >> 2, seg = tid & 3;
        int ev = evb + lr;
        int pos = s_side ? s_pos[ev] : d_pos[ev];
        const bf16x8* cp = (const bf16x8*)&C[lr * 136 + seg * 32];
        bf16x8* gp = (bf16x8*)(msg + (size_t)pos * 128 + seg * 32);
        gp[0] = cp[0];
        gp[1] = cp[1];
        gp[2] = cp[2];
        gp[3] = cp[3];
    }
}

// ---------------- fused mean-aggregation (sorted, contiguous) + GRU ----------------
__launch_bounds__(256, 3)
__global__ void k_gru(const unsigned short* __restrict__ msg,
                      const int* __restrict__ off, const int* __restrict__ cnt,
                      const float* __restrict__ memory,
                      const unsigned short* __restrict__ Wgf,
                      const float* __restrict__ bg,
                      float* __restrict__ out) {
    __shared__ __align__(16) unsigned short Xs[32 * 264];

    const int tid = threadIdx.x;
    const int n0 = blockIdx.x * 32;

    // aggregation: 8 threads/node, 16 feats each; msg rows contiguous per node
    {
        int g = tid >> 3, sub = tid & 7;
        int node = n0 + g;
        int beg = off[node], cn = cnt[node];
        float a[16];
#pragma unroll
        for (int i = 0; i < 16; ++i) a[i] = 0.0f;
        for (int m = 0; m < cn; ++m) {
            const bf16x8* p = (const bf16x8*)(msg + (size_t)(beg + m) * 128 + sub * 16);
            bf16x8 v0 = p[0], v1 = p[1];
#pragma unroll
            for (int k = 0; k < 8; ++k) {
                a[k]     += bf2f((unsigned short)v0[k]);
                a[8 + k] += bf2f((unsigned short)v1[k]);
            }
        }
        float inv = 1.0f / (float)(cn > 1 ? cn : 1);
#pragma unroll
        for (int i = 0; i < 16; ++i) a[i] *= inv;
        *(bf16x8*)&Xs[g * 264 + sub * 16] = pack8(&a[0]);
        *(bf16x8*)&Xs[g * 264 + sub * 16 + 8] = pack8(&a[8]);
        float f[16];
        const float4* mp = (const float4*)(memory + (size_t)node * 128 + sub * 16);
#pragma unroll
        for (int s = 0; s < 4; ++s) {
            float4 v = mp[s];
            f[s * 4 + 0] = v.x; f[s * 4 + 1] = v.y; f[s * 4 + 2] = v.z; f[s * 4 + 3] = v.w;
        }
        *(bf16x8*)&Xs[g * 264 + 128 + sub * 16] = pack8(&f[0]);
        *(bf16x8*)&Xs[g * 264 + 128 + sub * 16 + 8] = pack8(&f[8]);
    }
    __syncthreads();

    const int lane = tid & 63, w = tid >> 6;
    const int col0 = lane & 15, q = lane >> 4;

    f32x4 acc[2][4][2];   // [mt][gate][fh]
#pragma unroll
    for (int a = 0; a < 2; ++a)
#pragma unroll
        for (int g = 0; g < 4; ++g)
#pragma unroll
            for (int f = 0; f < 2; ++f)
#pragma unroll
                for (int i = 0; i < 4; ++i) acc[a][g][f][i] = 0.0f;

#pragma unroll
    for (int c = 0; c < 8; ++c) {
        bf16x8 bfr[4][2];
        const bf16x8* Wc = (const bf16x8*)Wgf + (size_t)c * 32 * 64;
#pragma unroll
        for (int g = 0; g < 4; ++g)
#pragma unroll
            for (int fh = 0; fh < 2; ++fh)
                bfr[g][fh] = Wc[(8 * g + 2 * w + fh) * 64 + lane];
        bf16x8 afr[2];
#pragma unroll
        for (int mt = 0; mt < 2; ++mt)
            afr[mt] = *(const bf16x8*)&Xs[(mt * 16 + col0) * 264 + c * 32 + q * 8];
#pragma unroll
        for (int mt = 0; mt < 2; ++mt)
#pragma unroll
            for (int g = 0; g < 4; ++g)
#pragma unroll
                for (int fh = 0; fh < 2; ++fh)
                    acc[mt][g][fh] = __builtin_amdgcn_mfma_f32_16x16x32_bf16(afr[mt], bfr[g][fh], acc[mt][g][fh], 0, 0, 0);
    }

    // epilogue: gates + blend
#pragma unroll
    for (int fh = 0; fh < 2; ++fh) {
        int feat = w * 32 + fh * 16 + col0;
        float b_r = bg[feat], b_z = bg[128 + feat], b_in = bg[256 + feat], b_hn = bg[384 + feat];
#pragma unroll
        for (int mt = 0; mt < 2; ++mt) {
#pragma unroll
            for (int r = 0; r < 4; ++r) {
                int node = n0 + mt * 16 + q * 4 + r;
                float rr = sigmoidf_(acc[mt][0][fh][r] + b_r);
                float zz = sigmoidf_(acc[mt][1][fh][r] + b_z);
                float nn = tanhf_((acc[mt][2][fh][r] + b_in) + rr * (acc[mt][3][fh][r] + b_hn));
                float h = memory[(size_t)node * 128 + feat];
                out[(size_t)node * 128 + feat] = (1.0f - zz) * nn + zz * h;
            }
        }
    }
}

// ---------------- last_update -> float output ----------------
__global__ void k_lu(const int* __restrict__ lu_tmp, float* __restrict__ outp) {
    int i = blockIdx.x * 256 + threadIdx.x;
    outp[i] = (float)lu_tmp[i];
}

extern "C" void kernel_launch(void* const* d_in, const int* in_sizes, int n_in,
                              void* d_out, int out_size, void* d_ws, size_t ws_size,
                              hipStream_t stream) {
    const float* memory = (const float*)d_in[0];
    const float* raw    = (const float*)d_in[1];
    const float* tw     = (const float*)d_in[2];
    const float* tb     = (const float*)d_in[3];
    const float* Wms    = (const float*)d_in[4];
    const float* bms    = (const float*)d_in[5];
    const float* Wmd    = (const float*)d_in[6];
    const float* bmd    = (const float*)d_in[7];
    const float* Wih    = (const float*)d_in[8];
    const float* Whh    = (const float*)d_in[9];
    const float* bih    = (const float*)d_in[10];
    const float* bhh    = (const float*)d_in[11];
    const int* src = (const int*)d_in[12];
    const int* dst = (const int*)d_in[13];
    const int* t   = (const int*)d_in[14];
    const int* lu  = (const int*)d_in[15];

    char* ws = (char*)d_ws;
    size_t ob = 0;
    unsigned short* memb = (unsigned short*)(ws + ob); ob += (size_t)NN * 128 * 2;       // 32 MB
    unsigned short* msg  = (unsigned short*)(ws + ob); ob += (size_t)2 * EE * 128 * 2;   // 128 MB (sorted)
    int* cnt             = (int*)(ws + ob);            ob += (size_t)NN * 4;
    int* off             = (int*)(ws + ob);            ob += (size_t)NN * 4;
    int* cursor          = (int*)(ws + ob);            ob += (size_t)NN * 4;
    int* lu_tmp          = (int*)(ws + ob);            ob += (size_t)NN * 4;
    int* pos2            = (int*)(ws + ob);            ob += (size_t)2 * EE * 4;         // 2 MB
    int* bsum            = (int*)(ws + ob);            ob += 512 * 4;
    int* boff            = (int*)(ws + ob);            ob += 512 * 4;
    unsigned short* Wmf  = (unsigned short*)(ws + ob); ob += (size_t)14 * 16 * 64 * 8 * 2;
    float* bm            = (float*)(ws + ob);          ob += 256 * 4;
    unsigned short* Wgf  = (unsigned short*)(ws + ob); ob += (size_t)8 * 32 * 64 * 8 * 2;
    float* bg            = (float*)(ws + ob);          ob += 512 * 4;

    float* out = (float*)d_out;
    // tenc lives in d_out (dead until k_gru/k_lu overwrite it): 32 MB <= 67 MB
    unsigned short* tenc_s = (unsigned short*)d_out;
    unsigned short* tenc_d = tenc_s + (size_t)EE * 32;

    hipMemsetAsync(cnt, 0, (size_t)NN * 4, stream);
    hipMemsetAsync(lu_tmp, 0, (size_t)NN * 4, stream);

    k_prep_msgfrag<<<14 * 16, 64, 0, stream>>>(Wms, Wmd, bms, bmd, Wmf, bm);
    k_prep_grufrag<<<8 * 32, 64, 0, stream>>>(Wih, Whh, bih, bhh, Wgf, bg);
    k_memconv<<<(NN * 128 / 4) / 256, 256, 0, stream>>>(memory, memb);
    k_tenc<<<(EE * 64) / 256, 256, 0, stream>>>(t, src, dst, lu, tw, tb, tenc_s, tenc_d);
    k_pre<<<EE / 256, 256, 0, stream>>>(src, dst, t, cnt, lu_tmp);
    k_scan1<<<512, 256, 0, stream>>>(cnt, bsum);
    k_scan2<<<1, 512, 0, stream>>>(bsum, boff);
    k_scan3<<<512, 256, 0, stream>>>(cnt, boff, off, cursor);
    k_fill<<<2 * EE / 256, 256, 0, stream>>>(src, dst, cursor, pos2);
    k_msg<<<EE / 128, 256, 0, stream>>>(memb, raw, tenc_s, tenc_d, Wmf, bm, src, dst, pos2, msg);
    k_gru<<<NN / 32, 256, 0, stream>>>(msg, off, cnt, memory, Wgf, bg, out);
    k_lu<<<NN / 256, 256, 0, stream>>>(lu_tmp, out + (size_t)NN * 128);
}